// Round 1
// baseline (539.305 us; speedup 1.0000x reference)
//
#include <hip/hip_runtime.h>

#define FDIM 256
#define ALPHA 0.2f

// ---------------- GEMM: h = x @ W  (fp32, 64x64 tile, 4x4 per thread) -------
__global__ __launch_bounds__(256) void gemm_f32(const float* __restrict__ A,
                                                const float* __restrict__ B,
                                                float* __restrict__ C, int M) {
  __shared__ float As[16][68];   // [k][m], +4 pad keeps float4 alignment, 2-way banks (free)
  __shared__ float Bs[16][64];   // [k][n]
  const int tid = threadIdx.x;
  const int tn = tid & 15, tm = tid >> 4;
  const int row0 = blockIdx.x * 64;
  const int ncol0 = blockIdx.y * 64;
  const int la_r = tid >> 2;          // 0..63
  const int la_k = (tid & 3) << 2;    // 0,4,8,12
  const int lb_k = tid >> 4;          // 0..15
  const int lb_n = (tid & 15) << 2;   // 0..60
  float acc[4][4] = {};
  for (int k0 = 0; k0 < 256; k0 += 16) {
    float4 av = make_float4(0.f, 0.f, 0.f, 0.f);
    const int ar = row0 + la_r;
    if (ar < M) av = *(const float4*)(A + (size_t)ar * 256 + k0 + la_k);
    As[la_k + 0][la_r] = av.x;
    As[la_k + 1][la_r] = av.y;
    As[la_k + 2][la_r] = av.z;
    As[la_k + 3][la_r] = av.w;
    *(float4*)(&Bs[lb_k][lb_n]) =
        *(const float4*)(B + (size_t)(k0 + lb_k) * 256 + ncol0 + lb_n);
    __syncthreads();
#pragma unroll
    for (int k = 0; k < 16; ++k) {
      float4 a4 = *(const float4*)(&As[k][tm << 2]);
      float4 b4 = *(const float4*)(&Bs[k][tn << 2]);
      float am[4] = {a4.x, a4.y, a4.z, a4.w};
      float bv[4] = {b4.x, b4.y, b4.z, b4.w};
#pragma unroll
      for (int i = 0; i < 4; ++i)
#pragma unroll
        for (int j = 0; j < 4; ++j) acc[i][j] += am[i] * bv[j];
    }
    __syncthreads();
  }
#pragma unroll
  for (int i = 0; i < 4; ++i) {
    const int r = row0 + (tm << 2) + i;
    if (r < M) {
      float4 v = make_float4(acc[i][0], acc[i][1], acc[i][2], acc[i][3]);
      *(float4*)(C + (size_t)r * 256 + ncol0 + (tn << 2)) = v;
    }
  }
}

// ---------------- s[i] = h[i] . a[0:256], t[i] = h[i] . a[256:512] ----------
__global__ __launch_bounds__(256) void st_kernel(const float* __restrict__ h,
                                                 const float* __restrict__ a,
                                                 float* __restrict__ s,
                                                 float* __restrict__ t, int n) {
  const int row = blockIdx.x * 4 + (threadIdx.x >> 6);
  const int lane = threadIdx.x & 63;
  if (row >= n) return;
  const float* hr = h + (size_t)row * 256;
  float sp = 0.f, tp = 0.f;
#pragma unroll
  for (int j = 0; j < 4; ++j) {
    const int c = lane + 64 * j;
    const float hv = hr[c];
    sp += hv * a[c];
    tp += hv * a[256 + c];
  }
#pragma unroll
  for (int off = 32; off > 0; off >>= 1) {
    sp += __shfl_down(sp, off);
    tp += __shfl_down(tp, off);
  }
  if (lane == 0) {
    s[row] = sp;
    t[row] = tp;
  }
}

// ---------------- CSR build: histogram, scan, scatter -----------------------
__global__ void hist_kernel(const int* __restrict__ edge, int* __restrict__ deg,
                            int E) {
  const int e = blockIdx.x * 256 + threadIdx.x;
  if (e < E) atomicAdd(&deg[edge[e]], 1);
}

__global__ __launch_bounds__(1024) void scan_kernel(const int* __restrict__ deg,
                                                    int* __restrict__ rowstart,
                                                    int n) {
  __shared__ int buf[1024];
  const int tid = threadIdx.x;
  if (tid == 0) rowstart[0] = 0;
  int carry = 0;
  for (int base = 0; base < n; base += 1024) {
    const int i = base + tid;
    buf[tid] = (i < n) ? deg[i] : 0;
    __syncthreads();
    for (int off = 1; off < 1024; off <<= 1) {
      const int add = (tid >= off) ? buf[tid - off] : 0;
      __syncthreads();
      buf[tid] += add;
      __syncthreads();
    }
    if (i < n) rowstart[i + 1] = carry + buf[tid];
    carry += buf[1023];
    __syncthreads();
  }
}

__global__ void scatter_kernel(const int* __restrict__ edge,
                               const int* __restrict__ rowstart,
                               int* __restrict__ cursor,
                               int* __restrict__ sdst, int E) {
  const int e = blockIdx.x * 256 + threadIdx.x;
  if (e < E) {
    const int src = edge[e];
    const int p = atomicAdd(&cursor[src], 1);
    sdst[rowstart[src] + p] = edge[E + e];  // store dst, segmented by src
  }
}

// ---------------- Aggregation: one block per row, no fp32 atomics -----------
__global__ __launch_bounds__(256) void agg_kernel(
    const float* __restrict__ h, const float* __restrict__ s,
    const float* __restrict__ t, const int* __restrict__ rowstart,
    const int* __restrict__ sdst, float* __restrict__ out, int n) {
  const int row = blockIdx.x;
  const int f = threadIdx.x;
  const int start = rowstart[row], end = rowstart[row + 1];
  const float srow = s[row];
  float acc = 0.f, rs = 0.f;
  for (int j = start; j < end; ++j) {
    const int dst = sdst[j];
    const float logit = srow + t[dst];
    const float lr = logit > 0.f ? logit : ALPHA * logit;
    const float ev = __expf(-lr);
    rs += ev;
    acc += ev * h[(size_t)dst * 256 + f];
  }
  const float v = acc / rs;
  out[(size_t)row * 256 + f] = v > 0.f ? v : 0.f;
}

extern "C" void kernel_launch(void* const* d_in, const int* in_sizes, int n_in,
                              void* d_out, int out_size, void* d_ws,
                              size_t ws_size, hipStream_t stream) {
  const float* x = (const float*)d_in[0];
  const int* edge = (const int*)d_in[1];
  const float* W = (const float*)d_in[2];
  const float* a = (const float*)d_in[3];
  float* out = (float*)d_out;
  const int N = in_sizes[0] / FDIM;   // 50000
  const int E = in_sizes[1] / 2;      // 850000

  // workspace layout
  float* h = (float*)d_ws;                    // N*256 floats (51.2 MB)
  float* s = h + (size_t)N * FDIM;            // N
  float* t = s + N;                           // N
  int* deg = (int*)(t + N);                   // N
  int* cursor = deg + N;                      // N (contiguous with deg)
  int* rowstart = cursor + N;                 // N+1
  int* sdst = rowstart + N + 1;               // E

  hipMemsetAsync(deg, 0, (size_t)2 * N * sizeof(int), stream);  // deg + cursor

  gemm_f32<<<dim3((N + 63) / 64, 4), 256, 0, stream>>>(x, W, h, N);
  st_kernel<<<(N + 3) / 4, 256, 0, stream>>>(h, a, s, t, N);
  hist_kernel<<<(E + 255) / 256, 256, 0, stream>>>(edge, deg, E);
  scan_kernel<<<1, 1024, 0, stream>>>(deg, rowstart, N);
  scatter_kernel<<<(E + 255) / 256, 256, 0, stream>>>(edge, rowstart, cursor,
                                                      sdst, E);
  agg_kernel<<<N, 256, 0, stream>>>(h, s, t, rowstart, sdst, out, N);
}

// Round 2
// 455.761 us; speedup vs baseline: 1.1833x; 1.1833x over previous
//
#include <hip/hip_runtime.h>
#include <hip/hip_fp16.h>

#define FDIM 256
#define ALPHA 0.2f

// ---------------- GEMM: h = x @ W  (fp32 math, fp16 output) -----------------
__global__ __launch_bounds__(256) void gemm_f32(const float* __restrict__ A,
                                                const float* __restrict__ B,
                                                __half* __restrict__ C, int M) {
  __shared__ float As[16][68];
  __shared__ float Bs[16][64];
  const int tid = threadIdx.x;
  const int tn = tid & 15, tm = tid >> 4;
  const int row0 = blockIdx.x * 64;
  const int ncol0 = blockIdx.y * 64;
  const int la_r = tid >> 2;
  const int la_k = (tid & 3) << 2;
  const int lb_k = tid >> 4;
  const int lb_n = (tid & 15) << 2;
  float acc[4][4] = {};
  for (int k0 = 0; k0 < 256; k0 += 16) {
    float4 av = make_float4(0.f, 0.f, 0.f, 0.f);
    const int ar = row0 + la_r;
    if (ar < M) av = *(const float4*)(A + (size_t)ar * 256 + k0 + la_k);
    As[la_k + 0][la_r] = av.x;
    As[la_k + 1][la_r] = av.y;
    As[la_k + 2][la_r] = av.z;
    As[la_k + 3][la_r] = av.w;
    *(float4*)(&Bs[lb_k][lb_n]) =
        *(const float4*)(B + (size_t)(k0 + lb_k) * 256 + ncol0 + lb_n);
    __syncthreads();
#pragma unroll
    for (int k = 0; k < 16; ++k) {
      float4 a4 = *(const float4*)(&As[k][tm << 2]);
      float4 b4 = *(const float4*)(&Bs[k][tn << 2]);
      float am[4] = {a4.x, a4.y, a4.z, a4.w};
      float bv[4] = {b4.x, b4.y, b4.z, b4.w};
#pragma unroll
      for (int i = 0; i < 4; ++i)
#pragma unroll
        for (int j = 0; j < 4; ++j) acc[i][j] += am[i] * bv[j];
    }
    __syncthreads();
  }
#pragma unroll
  for (int i = 0; i < 4; ++i) {
    const int r = row0 + (tm << 2) + i;
    if (r < M) {
      __half2 p0 = __floats2half2_rn(acc[i][0], acc[i][1]);
      __half2 p1 = __floats2half2_rn(acc[i][2], acc[i][3]);
      __half2* dst = (__half2*)(C + (size_t)r * 256 + ncol0 + (tn << 2));
      dst[0] = p0;
      dst[1] = p1;
    }
  }
}

// ---------------- s[i] = h[i] . a[0:256], t[i] = h[i] . a[256:512] ----------
__global__ __launch_bounds__(256) void st_kernel(const __half* __restrict__ h,
                                                 const float* __restrict__ a,
                                                 float* __restrict__ s,
                                                 float* __restrict__ t, int n) {
  const int row = blockIdx.x * 4 + (threadIdx.x >> 6);
  const int lane = threadIdx.x & 63;
  if (row >= n) return;
  const __half* hr = h + (size_t)row * 256;
  float sp = 0.f, tp = 0.f;
#pragma unroll
  for (int j = 0; j < 4; ++j) {
    const int c = lane + 64 * j;
    const float hv = __half2float(hr[c]);
    sp += hv * a[c];
    tp += hv * a[256 + c];
  }
#pragma unroll
  for (int off = 32; off > 0; off >>= 1) {
    sp += __shfl_down(sp, off);
    tp += __shfl_down(tp, off);
  }
  if (lane == 0) {
    s[row] = sp;
    t[row] = tp;
  }
}

// ---------------- CSR build -------------------------------------------------
__global__ void hist_kernel(const int* __restrict__ edge, int* __restrict__ deg,
                            int E) {
  const int e = blockIdx.x * 256 + threadIdx.x;
  if (e < E) atomicAdd(&deg[edge[e]], 1);
}

// single-block chunked scan: each thread owns a contiguous chunk
__global__ __launch_bounds__(1024) void scan_kernel(const int* __restrict__ deg,
                                                    int* __restrict__ rowstart,
                                                    int n) {
  const int tid = threadIdx.x;
  const int chunk = (n + 1023) >> 10;
  const int base = tid * chunk;
  int sum = 0;
  for (int i = 0; i < chunk; ++i) {
    const int idx = base + i;
    if (idx < n) sum += deg[idx];
  }
  // inclusive scan of per-thread sums: wave shuffle scan + cross-wave via LDS
  const int lane = tid & 63, wv = tid >> 6;
  int v = sum;
#pragma unroll
  for (int off = 1; off < 64; off <<= 1) {
    const int o = __shfl_up(v, off);
    if (lane >= off) v += o;
  }
  __shared__ int wsum[16];
  __shared__ int woff[16];
  if (lane == 63) wsum[wv] = v;
  __syncthreads();
  if (tid < 16) {
    int w = wsum[tid];
#pragma unroll
    for (int off = 1; off < 16; off <<= 1) {
      const int o = __shfl_up(w, off);
      if (tid >= off) w += o;
    }
    woff[tid] = w;  // inclusive
  }
  __syncthreads();
  int run = v - sum + (wv ? woff[wv - 1] : 0);  // exclusive prefix of chunk
  for (int i = 0; i < chunk; ++i) {
    const int idx = base + i;
    if (idx < n) {
      rowstart[idx] = run;
      run += deg[idx];
    }
  }
  if (tid == 0) rowstart[n] = woff[15];
}

// scatter edges into CSR order AND precompute e = exp(-leakyrelu(s+t))
__global__ void scatter_kernel(const int* __restrict__ edge,
                               const int* __restrict__ rowstart,
                               int* __restrict__ cursor,
                               const float* __restrict__ s,
                               const float* __restrict__ t,
                               int* __restrict__ sdst, float* __restrict__ se,
                               int E) {
  const int e = blockIdx.x * 256 + threadIdx.x;
  if (e < E) {
    const int src = edge[e];
    const int dst = edge[E + e];
    const float logit = s[src] + t[dst];
    const float lr = logit > 0.f ? logit : ALPHA * logit;
    const float ev = __expf(-lr);
    const int p = atomicAdd(&cursor[src], 1);
    const int pos = rowstart[src] + p;
    sdst[pos] = dst;
    se[pos] = ev;
  }
}

// ---------------- Aggregation: one block per row, unroll-4, fp16 gather -----
__global__ __launch_bounds__(256) void agg_kernel(
    const __half* __restrict__ h, const int* __restrict__ rowstart,
    const int* __restrict__ sdst, const float* __restrict__ se,
    float* __restrict__ out, int n) {
  const int row = blockIdx.x;
  const int f = threadIdx.x;
  const int start = rowstart[row], end = rowstart[row + 1];
  float acc = 0.f, rs = 0.f;
  int j = start;
  for (; j + 3 < end; j += 4) {
    const int d0 = sdst[j], d1 = sdst[j + 1], d2 = sdst[j + 2],
              d3 = sdst[j + 3];
    const float e0 = se[j], e1 = se[j + 1], e2 = se[j + 2], e3 = se[j + 3];
    const float v0 = __half2float(h[(size_t)d0 * 256 + f]);
    const float v1 = __half2float(h[(size_t)d1 * 256 + f]);
    const float v2 = __half2float(h[(size_t)d2 * 256 + f]);
    const float v3 = __half2float(h[(size_t)d3 * 256 + f]);
    rs += (e0 + e1) + (e2 + e3);
    acc += e0 * v0;
    acc += e1 * v1;
    acc += e2 * v2;
    acc += e3 * v3;
  }
  for (; j < end; ++j) {
    const int d = sdst[j];
    const float ev = se[j];
    rs += ev;
    acc += ev * __half2float(h[(size_t)d * 256 + f]);
  }
  const float v = acc / rs;
  out[(size_t)row * 256 + f] = v > 0.f ? v : 0.f;
}

extern "C" void kernel_launch(void* const* d_in, const int* in_sizes, int n_in,
                              void* d_out, int out_size, void* d_ws,
                              size_t ws_size, hipStream_t stream) {
  const float* x = (const float*)d_in[0];
  const int* edge = (const int*)d_in[1];
  const float* W = (const float*)d_in[2];
  const float* a = (const float*)d_in[3];
  float* out = (float*)d_out;
  const int N = in_sizes[0] / FDIM;  // 50000
  const int E = in_sizes[1] / 2;     // 850000

  // workspace layout
  __half* h = (__half*)d_ws;                    // N*256 halves (25.6 MB)
  float* s = (float*)(h + (size_t)N * FDIM);    // N
  float* t = s + N;                             // N
  int* deg = (int*)(t + N);                     // N
  int* cursor = deg + N;                        // N
  int* rowstart = cursor + N;                   // N+1
  int* sdst = rowstart + N + 1;                 // E
  float* se = (float*)(sdst + E);               // E

  hipMemsetAsync(deg, 0, (size_t)2 * N * sizeof(int), stream);  // deg+cursor

  gemm_f32<<<dim3((N + 63) / 64, 4), 256, 0, stream>>>(x, W, h, N);
  st_kernel<<<(N + 3) / 4, 256, 0, stream>>>(h, a, s, t, N);
  hist_kernel<<<(E + 255) / 256, 256, 0, stream>>>(edge, deg, E);
  scan_kernel<<<1, 1024, 0, stream>>>(deg, rowstart, N);
  scatter_kernel<<<(E + 255) / 256, 256, 0, stream>>>(edge, rowstart, cursor, s,
                                                      t, sdst, se, E);
  agg_kernel<<<N, 256, 0, stream>>>(h, rowstart, sdst, se, out, N);
}

// Round 3
// 441.719 us; speedup vs baseline: 1.2209x; 1.0318x over previous
//
#include <hip/hip_runtime.h>
#include <hip/hip_fp16.h>

#define FDIM 256
#define ALPHA 0.2f

typedef _Float16 half8 __attribute__((ext_vector_type(8)));
typedef float floatx4 __attribute__((ext_vector_type(4)));

// ---------------- prep: wswz = W^T, fp16, XOR-swizzled 16B chunks -----------
// Layout: for k-chunk kc (64 k's), chunk L = n*8 + c' holds W[kc*64 + c*8 + j][n],
// j=0..7, where c = c' ^ (n&7). 4 kc * 2048 chunks * 16B = 128 KB.
__global__ __launch_bounds__(256) void prep_w(const float* __restrict__ W,
                                              _Float16* __restrict__ wswz) {
  const int g = blockIdx.x * 256 + threadIdx.x;  // 0..8191
  const int kc = g >> 11, L = g & 2047;
  const int n = L >> 3, cp = L & 7;
  const int c = cp ^ (n & 7);
  half8 hv;
#pragma unroll
  for (int j = 0; j < 8; ++j)
    hv[j] = (_Float16)W[(size_t)(kc * 64 + c * 8 + j) * 256 + n];
  *(half8*)(wswz + (size_t)g * 8) = hv;
}

// ---------------- GEMM: h = x @ W via MFMA fp16, fused s/t epilogue ---------
// block = 256 thr (4 waves); tile 64 rows x 256 cols (full width, x read once).
// wave w owns cols [64w, 64w+64): 4x4 grid of 16x16 acc tiles.
__global__ __launch_bounds__(256) void gemm_mfma(
    const float* __restrict__ x, const _Float16* __restrict__ wswz,
    const float* __restrict__ a, __half* __restrict__ h,
    float* __restrict__ s, float* __restrict__ t, int M) {
  __shared__ __align__(16) _Float16 As[64 * 64];   // 8 KB, XOR-swizzled chunks
  __shared__ __align__(16) _Float16 Bs[256 * 64];  // 32 KB, XOR-swizzled chunks
  const int tid = threadIdx.x;
  const int w = tid >> 6, l = tid & 63;
  const int l15 = l & 15, q = l >> 4;
  const int row0 = blockIdx.x * 64;

  floatx4 acc[4][4];
#pragma unroll
  for (int mt = 0; mt < 4; ++mt)
#pragma unroll
    for (int nt = 0; nt < 4; ++nt) acc[mt][nt] = (floatx4){0.f, 0.f, 0.f, 0.f};

  for (int kc = 0; kc < 4; ++kc) {
    // A stage: 512 chunks of 16B; chunk id = m*8 + c', c = c' ^ (m&7)
#pragma unroll
    for (int hf = 0; hf < 2; ++hf) {
      const int id = hf * 256 + tid;
      const int m = id >> 3, cp = id & 7;
      const int c = cp ^ (m & 7);
      const int row = row0 + m;
      float4 f0 = make_float4(0.f, 0.f, 0.f, 0.f);
      float4 f1 = make_float4(0.f, 0.f, 0.f, 0.f);
      if (row < M) {
        const float4* p = (const float4*)(x + (size_t)row * 256 + kc * 64 + c * 8);
        f0 = p[0];
        f1 = p[1];
      }
      half8 hv;
      hv[0] = (_Float16)f0.x; hv[1] = (_Float16)f0.y;
      hv[2] = (_Float16)f0.z; hv[3] = (_Float16)f0.w;
      hv[4] = (_Float16)f1.x; hv[5] = (_Float16)f1.y;
      hv[6] = (_Float16)f1.z; hv[7] = (_Float16)f1.w;
      *(half8*)(As + (size_t)id * 8) = hv;
    }
    // B stage: copy precomputed 32 KB image (coalesced 16B per thread)
    const _Float16* bsrc = wswz + (size_t)kc * 2048 * 8;
#pragma unroll
    for (int j = 0; j < 8; ++j) {
      const int idx = j * 256 + tid;
      *(half8*)(Bs + (size_t)idx * 8) = *(const half8*)(bsrc + (size_t)idx * 8);
    }
    __syncthreads();
#pragma unroll
    for (int ks = 0; ks < 2; ++ks) {
      const int c = ks * 4 + q;
      half8 af[4], bf[4];
#pragma unroll
      for (int mt = 0; mt < 4; ++mt) {
        const int m = mt * 16 + l15;
        af[mt] = *(const half8*)(As + (size_t)(m * 8 + (c ^ (m & 7))) * 8);
      }
#pragma unroll
      for (int nt = 0; nt < 4; ++nt) {
        const int n = w * 64 + nt * 16 + l15;
        bf[nt] = *(const half8*)(Bs + (size_t)(n * 8 + (c ^ (n & 7))) * 8);
      }
#pragma unroll
      for (int mt = 0; mt < 4; ++mt)
#pragma unroll
        for (int nt = 0; nt < 4; ++nt)
          acc[mt][nt] = __builtin_amdgcn_mfma_f32_16x16x32_f16(
              af[mt], bf[nt], acc[mt][nt], 0, 0, 0);
    }
    __syncthreads();
  }

  // write h (C/D layout: row = q*4 + r, col = l15)
#pragma unroll
  for (int mt = 0; mt < 4; ++mt)
#pragma unroll
    for (int r = 0; r < 4; ++r) {
      const int row = row0 + mt * 16 + q * 4 + r;
      if (row < M) {
#pragma unroll
        for (int nt = 0; nt < 4; ++nt) {
          const int col = w * 64 + nt * 16 + l15;
          h[(size_t)row * 256 + col] = __float2half(acc[mt][nt][r]);
        }
      }
    }

  // fused s/t: s[row] = h[row].a[0:256], t[row] = h[row].a[256:512]
  float* sbuf = (float*)As;  // reuse As (all reads done, synced above)
  float* tbuf = sbuf + 64;
  if (tid < 128) sbuf[tid] = 0.f;
  __syncthreads();
  float av[4], av2[4];
#pragma unroll
  for (int nt = 0; nt < 4; ++nt) {
    const int col = w * 64 + nt * 16 + l15;
    av[nt] = a[col];
    av2[nt] = a[256 + col];
  }
#pragma unroll
  for (int mt = 0; mt < 4; ++mt)
#pragma unroll
    for (int r = 0; r < 4; ++r) {
      float sp = 0.f, tp = 0.f;
#pragma unroll
      for (int nt = 0; nt < 4; ++nt) {
        sp += acc[mt][nt][r] * av[nt];
        tp += acc[mt][nt][r] * av2[nt];
      }
      const int ml = mt * 16 + q * 4 + r;
      atomicAdd(&sbuf[ml], sp);
      atomicAdd(&tbuf[ml], tp);
    }
  __syncthreads();
  if (tid < 64) {
    const int row = row0 + tid;
    if (row < M) {
      s[row] = sbuf[tid];
      t[row] = tbuf[tid];
    }
  }
}

// ---------------- CSR build -------------------------------------------------
__global__ void hist_kernel(const int* __restrict__ edge, int* __restrict__ deg,
                            int E) {
  const int e = blockIdx.x * 256 + threadIdx.x;
  if (e < E) atomicAdd(&deg[edge[e]], 1);
}

__global__ __launch_bounds__(1024) void scan_kernel(const int* __restrict__ deg,
                                                    int* __restrict__ rowstart,
                                                    int n) {
  const int tid = threadIdx.x;
  const int chunk = (n + 1023) >> 10;
  const int base = tid * chunk;
  int sum = 0;
  for (int i = 0; i < chunk; ++i) {
    const int idx = base + i;
    if (idx < n) sum += deg[idx];
  }
  const int lane = tid & 63, wv = tid >> 6;
  int v = sum;
#pragma unroll
  for (int off = 1; off < 64; off <<= 1) {
    const int o = __shfl_up(v, off);
    if (lane >= off) v += o;
  }
  __shared__ int wsum[16];
  __shared__ int woff[16];
  if (lane == 63) wsum[wv] = v;
  __syncthreads();
  if (tid < 16) {
    int wv2 = wsum[tid];
#pragma unroll
    for (int off = 1; off < 16; off <<= 1) {
      const int o = __shfl_up(wv2, off);
      if (tid >= off) wv2 += o;
    }
    woff[tid] = wv2;
  }
  __syncthreads();
  int run = v - sum + (wv ? woff[wv - 1] : 0);
  for (int i = 0; i < chunk; ++i) {
    const int idx = base + i;
    if (idx < n) {
      rowstart[idx] = run;
      run += deg[idx];
    }
  }
  if (tid == 0) rowstart[n] = woff[15];
}

__global__ void scatter_kernel(const int* __restrict__ edge,
                               const int* __restrict__ rowstart,
                               int* __restrict__ cursor,
                               const float* __restrict__ s,
                               const float* __restrict__ t,
                               int* __restrict__ sdst, float* __restrict__ se,
                               int E) {
  const int e = blockIdx.x * 256 + threadIdx.x;
  if (e < E) {
    const int src = edge[e];
    const int dst = edge[E + e];
    const float logit = s[src] + t[dst];
    const float lr = logit > 0.f ? logit : ALPHA * logit;
    const float ev = __expf(-lr);
    const int p = atomicAdd(&cursor[src], 1);
    const int pos = rowstart[src] + p;
    sdst[pos] = dst;
    se[pos] = ev;
  }
}

// ---------------- Aggregation: one block per row, unroll-4, fp16 gather -----
__global__ __launch_bounds__(256) void agg_kernel(
    const __half* __restrict__ h, const int* __restrict__ rowstart,
    const int* __restrict__ sdst, const float* __restrict__ se,
    float* __restrict__ out, int n) {
  const int row = blockIdx.x;
  const int f = threadIdx.x;
  const int start = rowstart[row], end = rowstart[row + 1];
  float acc = 0.f, rs = 0.f;
  int j = start;
  for (; j + 3 < end; j += 4) {
    const int d0 = sdst[j], d1 = sdst[j + 1], d2 = sdst[j + 2],
              d3 = sdst[j + 3];
    const float e0 = se[j], e1 = se[j + 1], e2 = se[j + 2], e3 = se[j + 3];
    const float v0 = __half2float(h[(size_t)d0 * 256 + f]);
    const float v1 = __half2float(h[(size_t)d1 * 256 + f]);
    const float v2 = __half2float(h[(size_t)d2 * 256 + f]);
    const float v3 = __half2float(h[(size_t)d3 * 256 + f]);
    rs += (e0 + e1) + (e2 + e3);
    acc += e0 * v0;
    acc += e1 * v1;
    acc += e2 * v2;
    acc += e3 * v3;
  }
  for (; j < end; ++j) {
    const int d = sdst[j];
    const float ev = se[j];
    rs += ev;
    acc += ev * __half2float(h[(size_t)d * 256 + f]);
  }
  const float v = acc / rs;
  out[(size_t)row * 256 + f] = v > 0.f ? v : 0.f;
}

extern "C" void kernel_launch(void* const* d_in, const int* in_sizes, int n_in,
                              void* d_out, int out_size, void* d_ws,
                              size_t ws_size, hipStream_t stream) {
  const float* x = (const float*)d_in[0];
  const int* edge = (const int*)d_in[1];
  const float* W = (const float*)d_in[2];
  const float* a = (const float*)d_in[3];
  float* out = (float*)d_out;
  const int N = in_sizes[0] / FDIM;  // 50000
  const int E = in_sizes[1] / 2;     // 850000

  // workspace layout (16B-aligned pieces first)
  __half* h = (__half*)d_ws;                        // N*256 halves (25.6 MB)
  _Float16* wswz = (_Float16*)(h + (size_t)N * FDIM);  // 16384 halves (128 KB... 8192*8)
  float* s = (float*)(wswz + 8192 * 8);             // N
  float* t = s + N;                                 // N
  int* deg = (int*)(t + N);                         // N
  int* cursor = deg + N;                            // N
  int* rowstart = cursor + N;                       // N+1
  int* sdst = rowstart + N + 1;                     // E
  float* se = (float*)(sdst + E);                   // E

  hipMemsetAsync(deg, 0, (size_t)2 * N * sizeof(int), stream);  // deg+cursor

  prep_w<<<32, 256, 0, stream>>>(W, wswz);
  gemm_mfma<<<(N + 63) / 64, 256, 0, stream>>>(x, wswz, a, h, s, t, N);
  hist_kernel<<<(E + 255) / 256, 256, 0, stream>>>(edge, deg, E);
  scan_kernel<<<1, 1024, 0, stream>>>(deg, rowstart, N);
  scatter_kernel<<<(E + 255) / 256, 256, 0, stream>>>(edge, rowstart, cursor, s,
                                                      t, sdst, se, E);
  agg_kernel<<<N, 256, 0, stream>>>(h, rowstart, sdst, se, out, N);
}

// Round 4
// 402.754 us; speedup vs baseline: 1.3390x; 1.0967x over previous
//
#include <hip/hip_runtime.h>
#include <hip/hip_fp16.h>

#define FDIM 256
#define ALPHA 0.2f

typedef _Float16 half8 __attribute__((ext_vector_type(8)));
typedef _Float16 half4 __attribute__((ext_vector_type(4)));
typedef float floatx4 __attribute__((ext_vector_type(4)));

// ---- prep W (fp16 chunked W^T image) + edge histogram, fused ---------------
// wswz chunk g = kc*2048 + n*8 + c holds W[kc*64 + c*8 + j][n], j=0..7.
__global__ __launch_bounds__(256) void prep_hist(const float* __restrict__ W,
                                                 _Float16* __restrict__ wswz,
                                                 const int* __restrict__ edge,
                                                 int* __restrict__ deg, int E) {
  if (blockIdx.x < 32) {
    const int g = blockIdx.x * 256 + threadIdx.x;  // 0..8191
    const int kc = g >> 11, L = g & 2047;
    const int n = L >> 3, c = L & 7;
    half8 hv;
#pragma unroll
    for (int j = 0; j < 8; ++j)
      hv[j] = (_Float16)W[(size_t)(kc * 64 + c * 8 + j) * 256 + n];
    *(half8*)(wswz + (size_t)g * 8) = hv;
  } else {
    const int e = (blockIdx.x - 32) * 256 + threadIdx.x;
    if (e < E) atomicAdd(&deg[edge[e]], 1);
  }
}

// ---- GEMM h = x@W, MFMA fp16, A reg-double-buffered, B direct from L2 ------
__global__ __launch_bounds__(256) void gemm_mfma(
    const float* __restrict__ x, const _Float16* __restrict__ wswz,
    const float* __restrict__ a, __half* __restrict__ h,
    float* __restrict__ s, float* __restrict__ t, int M) {
  __shared__ __align__(16) _Float16 As[64 * 64];  // 8 KB, XOR-swizzled chunks
  const int tid = threadIdx.x;
  const int w = tid >> 6, l = tid & 63;
  const int l15 = l & 15, q = l >> 4;
  const int row0 = blockIdx.x * 64;

  floatx4 acc[4][4];
#pragma unroll
  for (int mt = 0; mt < 4; ++mt)
#pragma unroll
    for (int nt = 0; nt < 4; ++nt) acc[mt][nt] = (floatx4){0.f, 0.f, 0.f, 0.f};

  // A-stage addressing: chunk id = m*8 + c', with c = c' ^ (m&7)
  const int id0 = tid, id1 = 256 + tid;
  const int m0 = id0 >> 3, c0 = (id0 & 7) ^ (m0 & 7);
  const int m1 = id1 >> 3, c1 = (id1 & 7) ^ (m1 & 7);
  const int r0 = row0 + m0, r1 = row0 + m1;

  float4 pf[2][2];
  auto loadA = [&](int kc) {
    pf[0][0] = pf[0][1] = pf[1][0] = pf[1][1] = make_float4(0.f, 0.f, 0.f, 0.f);
    if (r0 < M) {
      const float4* p = (const float4*)(x + (size_t)r0 * 256 + kc * 64 + c0 * 8);
      pf[0][0] = p[0];
      pf[0][1] = p[1];
    }
    if (r1 < M) {
      const float4* p = (const float4*)(x + (size_t)r1 * 256 + kc * 64 + c1 * 8);
      pf[1][0] = p[0];
      pf[1][1] = p[1];
    }
  };
  auto storeA = [&]() {
#pragma unroll
    for (int hf = 0; hf < 2; ++hf) {
      half8 hv;
      hv[0] = (_Float16)pf[hf][0].x; hv[1] = (_Float16)pf[hf][0].y;
      hv[2] = (_Float16)pf[hf][0].z; hv[3] = (_Float16)pf[hf][0].w;
      hv[4] = (_Float16)pf[hf][1].x; hv[5] = (_Float16)pf[hf][1].y;
      hv[6] = (_Float16)pf[hf][1].z; hv[7] = (_Float16)pf[hf][1].w;
      *(half8*)(As + (size_t)(hf * 256 + tid) * 8) = hv;
    }
  };

  loadA(0);
  for (int kc = 0; kc < 4; ++kc) {
    storeA();
    // B fragments straight from L2 (128 KB image, no LDS) — independent of barrier
    half8 bf[2][4];
#pragma unroll
    for (int ks = 0; ks < 2; ++ks) {
      const int c = ks * 4 + q;
#pragma unroll
      for (int nt = 0; nt < 4; ++nt) {
        const int n = w * 64 + nt * 16 + l15;
        bf[ks][nt] = *(const half8*)(wswz + (size_t)(kc * 2048 + n * 8 + c) * 8);
      }
    }
    __syncthreads();
    if (kc < 3) loadA(kc + 1);  // overlaps with MFMAs below
#pragma unroll
    for (int ks = 0; ks < 2; ++ks) {
      const int c = ks * 4 + q;
      half8 af[4];
#pragma unroll
      for (int mt = 0; mt < 4; ++mt) {
        const int m = mt * 16 + l15;
        af[mt] = *(const half8*)(As + (size_t)(m * 8 + (c ^ (m & 7))) * 8);
      }
#pragma unroll
      for (int mt = 0; mt < 4; ++mt)
#pragma unroll
        for (int nt = 0; nt < 4; ++nt)
          acc[mt][nt] = __builtin_amdgcn_mfma_f32_16x16x32_f16(
              af[mt], bf[ks][nt], acc[mt][nt], 0, 0, 0);
    }
    __syncthreads();
  }

  // write h (C/D layout: row = q*4 + r, col = l15)
#pragma unroll
  for (int mt = 0; mt < 4; ++mt)
#pragma unroll
    for (int r = 0; r < 4; ++r) {
      const int row = row0 + mt * 16 + q * 4 + r;
      if (row < M) {
#pragma unroll
        for (int nt = 0; nt < 4; ++nt) {
          const int col = w * 64 + nt * 16 + l15;
          h[(size_t)row * 256 + col] = __float2half(acc[mt][nt][r]);
        }
      }
    }

  // fused s/t epilogue
  float* sbuf = (float*)As;
  float* tbuf = sbuf + 64;
  if (tid < 128) sbuf[tid] = 0.f;
  __syncthreads();
  float av[4], av2[4];
#pragma unroll
  for (int nt = 0; nt < 4; ++nt) {
    const int col = w * 64 + nt * 16 + l15;
    av[nt] = a[col];
    av2[nt] = a[256 + col];
  }
#pragma unroll
  for (int mt = 0; mt < 4; ++mt)
#pragma unroll
    for (int r = 0; r < 4; ++r) {
      float sp = 0.f, tp = 0.f;
#pragma unroll
      for (int nt = 0; nt < 4; ++nt) {
        sp += acc[mt][nt][r] * av[nt];
        tp += acc[mt][nt][r] * av2[nt];
      }
      const int ml = mt * 16 + q * 4 + r;
      atomicAdd(&sbuf[ml], sp);
      atomicAdd(&tbuf[ml], tp);
    }
  __syncthreads();
  if (tid < 64) {
    const int row = row0 + tid;
    if (row < M) {
      s[row] = sbuf[tid];
      t[row] = tbuf[tid];
    }
  }
}

// ---- single-block chunked scan ---------------------------------------------
__global__ __launch_bounds__(1024) void scan_kernel(const int* __restrict__ deg,
                                                    int* __restrict__ rowstart,
                                                    int n) {
  const int tid = threadIdx.x;
  const int chunk = (n + 1023) >> 10;
  const int base = tid * chunk;
  int sum = 0;
  for (int i = 0; i < chunk; ++i) {
    const int idx = base + i;
    if (idx < n) sum += deg[idx];
  }
  const int lane = tid & 63, wv = tid >> 6;
  int v = sum;
#pragma unroll
  for (int off = 1; off < 64; off <<= 1) {
    const int o = __shfl_up(v, off);
    if (lane >= off) v += o;
  }
  __shared__ int wsum[16];
  __shared__ int woff[16];
  if (lane == 63) wsum[wv] = v;
  __syncthreads();
  if (tid < 16) {
    int wv2 = wsum[tid];
#pragma unroll
    for (int off = 1; off < 16; off <<= 1) {
      const int o = __shfl_up(wv2, off);
      if (tid >= off) wv2 += o;
    }
    woff[tid] = wv2;
  }
  __syncthreads();
  int run = v - sum + (wv ? woff[wv - 1] : 0);
  for (int i = 0; i < chunk; ++i) {
    const int idx = base + i;
    if (idx < n) {
      rowstart[idx] = run;
      run += deg[idx];
    }
  }
  if (tid == 0) rowstart[n] = woff[15];
}

// ---- scatter into CSR with precomputed e, packed (dst, e) 8B ---------------
__global__ void scatter_kernel(const int* __restrict__ edge,
                               const int* __restrict__ rowstart,
                               int* __restrict__ cursor,
                               const float* __restrict__ s,
                               const float* __restrict__ t,
                               int2* __restrict__ sde, int E) {
  const int e = blockIdx.x * 256 + threadIdx.x;
  if (e < E) {
    const int src = edge[e];
    const int dst = edge[E + e];
    const float logit = s[src] + t[dst];
    const float lr = logit > 0.f ? logit : ALPHA * logit;
    const float ev = __expf(-lr);
    const int p = atomicAdd(&cursor[src], 1);
    sde[rowstart[src] + p] = make_int2(dst, __float_as_int(ev));
  }
}

// ---- aggregation: wave per row, lane = 4 features, 8B gathers, unroll-4 ----
__global__ __launch_bounds__(256) void agg_kernel(
    const __half* __restrict__ h, const int* __restrict__ rowstart,
    const int2* __restrict__ sde, float* __restrict__ out, int n) {
  const int w = threadIdx.x >> 6, l = threadIdx.x & 63;
  const int row = blockIdx.x * 4 + w;
  if (row >= n) return;
  const int start = rowstart[row], end = rowstart[row + 1];
  const size_t fo = (size_t)l * 4;
  float a0 = 0.f, a1 = 0.f, a2 = 0.f, a3 = 0.f, rs = 0.f;
  int j = start;
  for (; j + 3 < end; j += 4) {
    const int2 p0 = sde[j], p1 = sde[j + 1], p2 = sde[j + 2], p3 = sde[j + 3];
    const half4 v0 = *(const half4*)(h + (size_t)p0.x * 256 + fo);
    const half4 v1 = *(const half4*)(h + (size_t)p1.x * 256 + fo);
    const half4 v2 = *(const half4*)(h + (size_t)p2.x * 256 + fo);
    const half4 v3 = *(const half4*)(h + (size_t)p3.x * 256 + fo);
    const float e0 = __int_as_float(p0.y), e1 = __int_as_float(p1.y);
    const float e2 = __int_as_float(p2.y), e3 = __int_as_float(p3.y);
    rs += (e0 + e1) + (e2 + e3);
    a0 += e0 * (float)v0[0] + e1 * (float)v1[0] + e2 * (float)v2[0] + e3 * (float)v3[0];
    a1 += e0 * (float)v0[1] + e1 * (float)v1[1] + e2 * (float)v2[1] + e3 * (float)v3[1];
    a2 += e0 * (float)v0[2] + e1 * (float)v1[2] + e2 * (float)v2[2] + e3 * (float)v3[2];
    a3 += e0 * (float)v0[3] + e1 * (float)v1[3] + e2 * (float)v2[3] + e3 * (float)v3[3];
  }
  for (; j < end; ++j) {
    const int2 p = sde[j];
    const half4 v = *(const half4*)(h + (size_t)p.x * 256 + fo);
    const float ev = __int_as_float(p.y);
    rs += ev;
    a0 += ev * (float)v[0];
    a1 += ev * (float)v[1];
    a2 += ev * (float)v[2];
    a3 += ev * (float)v[3];
  }
  const float inv = 1.f / rs;
  float4 o;
  o.x = a0 * inv; o.y = a1 * inv; o.z = a2 * inv; o.w = a3 * inv;
  o.x = o.x > 0.f ? o.x : 0.f;
  o.y = o.y > 0.f ? o.y : 0.f;
  o.z = o.z > 0.f ? o.z : 0.f;
  o.w = o.w > 0.f ? o.w : 0.f;
  *(float4*)(out + (size_t)row * 256 + fo) = o;
}

extern "C" void kernel_launch(void* const* d_in, const int* in_sizes, int n_in,
                              void* d_out, int out_size, void* d_ws,
                              size_t ws_size, hipStream_t stream) {
  const float* x = (const float*)d_in[0];
  const int* edge = (const int*)d_in[1];
  const float* W = (const float*)d_in[2];
  const float* a = (const float*)d_in[3];
  float* out = (float*)d_out;
  const int N = in_sizes[0] / FDIM;  // 50000
  const int E = in_sizes[1] / 2;     // 850000

  // workspace layout (keep 8B alignment for sde)
  __half* h = (__half*)d_ws;                           // N*256 fp16
  _Float16* wswz = (_Float16*)(h + (size_t)N * FDIM);  // 65536 halves (128 KB)
  float* s = (float*)(wswz + 8192 * 8);                // N
  float* t = s + N;                                    // N
  int* deg = (int*)(t + N);                            // N
  int* cursor = deg + N;                               // N
  int* rowstart = cursor + N;                          // N+2 (pad, even)
  int2* sde = (int2*)(rowstart + N + 2);               // E packed (dst, e)

  hipMemsetAsync(deg, 0, (size_t)2 * N * sizeof(int), stream);  // deg+cursor

  prep_hist<<<32 + (E + 255) / 256, 256, 0, stream>>>(W, wswz, edge, deg, E);
  gemm_mfma<<<(N + 63) / 64, 256, 0, stream>>>(x, wswz, a, h, s, t, N);
  scan_kernel<<<1, 1024, 0, stream>>>(deg, rowstart, N);
  scatter_kernel<<<(E + 255) / 256, 256, 0, stream>>>(edge, rowstart, cursor, s,
                                                      t, sde, E);
  agg_kernel<<<(N + 3) / 4, 256, 0, stream>>>(h, rowstart, sde, out, N);
}

// Round 5
// 318.957 us; speedup vs baseline: 1.6908x; 1.2627x over previous
//
#include <hip/hip_runtime.h>
#include <hip/hip_fp16.h>

#define FDIM 256
#define ALPHA 0.2f

typedef _Float16 half8 __attribute__((ext_vector_type(8)));
typedef _Float16 half4 __attribute__((ext_vector_type(4)));
typedef float floatx4 __attribute__((ext_vector_type(4)));

// ---- prep W (fp16 chunked W^T image) + edge histogram, fused ---------------
__global__ __launch_bounds__(256) void prep_hist(const float* __restrict__ W,
                                                 _Float16* __restrict__ wswz,
                                                 const int* __restrict__ edge,
                                                 int* __restrict__ deg, int E) {
  if (blockIdx.x < 32) {
    const int g = blockIdx.x * 256 + threadIdx.x;  // 0..8191
    const int kc = g >> 11, L = g & 2047;
    const int n = L >> 3, c = L & 7;
    half8 hv;
#pragma unroll
    for (int j = 0; j < 8; ++j)
      hv[j] = (_Float16)W[(size_t)(kc * 64 + c * 8 + j) * 256 + n];
    *(half8*)(wswz + (size_t)g * 8) = hv;
  } else {
    const int e = (blockIdx.x - 32) * 256 + threadIdx.x;
    if (e < E) atomicAdd(&deg[edge[e]], 1);
  }
}

// ---- GEMM h = x@W, MFMA fp16, A reg-double-buffered, B direct from L2 ------
__global__ __launch_bounds__(256) void gemm_mfma(
    const float* __restrict__ x, const _Float16* __restrict__ wswz,
    const float* __restrict__ a, __half* __restrict__ h,
    float* __restrict__ s, float* __restrict__ t, int M) {
  __shared__ __align__(16) _Float16 As[64 * 64];  // 8 KB, XOR-swizzled chunks
  const int tid = threadIdx.x;
  const int w = tid >> 6, l = tid & 63;
  const int l15 = l & 15, q = l >> 4;
  const int row0 = blockIdx.x * 64;

  floatx4 acc[4][4];
#pragma unroll
  for (int mt = 0; mt < 4; ++mt)
#pragma unroll
    for (int nt = 0; nt < 4; ++nt) acc[mt][nt] = (floatx4){0.f, 0.f, 0.f, 0.f};

  const int id0 = tid, id1 = 256 + tid;
  const int m0 = id0 >> 3, c0 = (id0 & 7) ^ (m0 & 7);
  const int m1 = id1 >> 3, c1 = (id1 & 7) ^ (m1 & 7);
  const int r0 = row0 + m0, r1 = row0 + m1;

  float4 pf[2][2];
  auto loadA = [&](int kc) {
    pf[0][0] = pf[0][1] = pf[1][0] = pf[1][1] = make_float4(0.f, 0.f, 0.f, 0.f);
    if (r0 < M) {
      const float4* p = (const float4*)(x + (size_t)r0 * 256 + kc * 64 + c0 * 8);
      pf[0][0] = p[0];
      pf[0][1] = p[1];
    }
    if (r1 < M) {
      const float4* p = (const float4*)(x + (size_t)r1 * 256 + kc * 64 + c1 * 8);
      pf[1][0] = p[0];
      pf[1][1] = p[1];
    }
  };
  auto storeA = [&]() {
#pragma unroll
    for (int hf = 0; hf < 2; ++hf) {
      half8 hv;
      hv[0] = (_Float16)pf[hf][0].x; hv[1] = (_Float16)pf[hf][0].y;
      hv[2] = (_Float16)pf[hf][0].z; hv[3] = (_Float16)pf[hf][0].w;
      hv[4] = (_Float16)pf[hf][1].x; hv[5] = (_Float16)pf[hf][1].y;
      hv[6] = (_Float16)pf[hf][1].z; hv[7] = (_Float16)pf[hf][1].w;
      *(half8*)(As + (size_t)(hf * 256 + tid) * 8) = hv;
    }
  };

  loadA(0);
  for (int kc = 0; kc < 4; ++kc) {
    storeA();
    half8 bf[2][4];
#pragma unroll
    for (int ks = 0; ks < 2; ++ks) {
      const int c = ks * 4 + q;
#pragma unroll
      for (int nt = 0; nt < 4; ++nt) {
        const int n = w * 64 + nt * 16 + l15;
        bf[ks][nt] = *(const half8*)(wswz + (size_t)(kc * 2048 + n * 8 + c) * 8);
      }
    }
    __syncthreads();
    if (kc < 3) loadA(kc + 1);
#pragma unroll
    for (int ks = 0; ks < 2; ++ks) {
      const int c = ks * 4 + q;
      half8 af[4];
#pragma unroll
      for (int mt = 0; mt < 4; ++mt) {
        const int m = mt * 16 + l15;
        af[mt] = *(const half8*)(As + (size_t)(m * 8 + (c ^ (m & 7))) * 8);
      }
#pragma unroll
      for (int mt = 0; mt < 4; ++mt)
#pragma unroll
        for (int nt = 0; nt < 4; ++nt)
          acc[mt][nt] = __builtin_amdgcn_mfma_f32_16x16x32_f16(
              af[mt], bf[ks][nt], acc[mt][nt], 0, 0, 0);
    }
    __syncthreads();
  }

#pragma unroll
  for (int mt = 0; mt < 4; ++mt)
#pragma unroll
    for (int r = 0; r < 4; ++r) {
      const int row = row0 + mt * 16 + q * 4 + r;
      if (row < M) {
#pragma unroll
        for (int nt = 0; nt < 4; ++nt) {
          const int col = w * 64 + nt * 16 + l15;
          h[(size_t)row * 256 + col] = __float2half(acc[mt][nt][r]);
        }
      }
    }

  float* sbuf = (float*)As;
  float* tbuf = sbuf + 64;
  if (tid < 128) sbuf[tid] = 0.f;
  __syncthreads();
  float av[4], av2[4];
#pragma unroll
  for (int nt = 0; nt < 4; ++nt) {
    const int col = w * 64 + nt * 16 + l15;
    av[nt] = a[col];
    av2[nt] = a[256 + col];
  }
#pragma unroll
  for (int mt = 0; mt < 4; ++mt)
#pragma unroll
    for (int r = 0; r < 4; ++r) {
      float sp = 0.f, tp = 0.f;
#pragma unroll
      for (int nt = 0; nt < 4; ++nt) {
        sp += acc[mt][nt][r] * av[nt];
        tp += acc[mt][nt][r] * av2[nt];
      }
      const int ml = mt * 16 + q * 4 + r;
      atomicAdd(&sbuf[ml], sp);
      atomicAdd(&tbuf[ml], tp);
    }
  __syncthreads();
  if (tid < 64) {
    const int row = row0 + tid;
    if (row < M) {
      s[row] = sbuf[tid];
      t[row] = tbuf[tid];
    }
  }
}

// ---- multi-block scan: phase 1 — per-block exclusive scan + block sums -----
__global__ __launch_bounds__(1024) void scan1(const int* __restrict__ deg,
                                              int* __restrict__ rowstart,
                                              int* __restrict__ bsum, int n) {
  const int tid = threadIdx.x;
  const int i = blockIdx.x * 1024 + tid;
  const int val = (i < n) ? deg[i] : 0;
  const int lane = tid & 63, wv = tid >> 6;
  int v = val;
#pragma unroll
  for (int off = 1; off < 64; off <<= 1) {
    const int o = __shfl_up(v, off);
    if (lane >= off) v += o;
  }
  __shared__ int wsum[16];
  __shared__ int woff[16];
  if (lane == 63) wsum[wv] = v;
  __syncthreads();
  if (tid < 16) {
    int wv2 = wsum[tid];
#pragma unroll
    for (int off = 1; off < 16; off <<= 1) {
      const int o = __shfl_up(wv2, off);
      if (tid >= off) wv2 += o;
    }
    woff[tid] = wv2;
  }
  __syncthreads();
  const int incl = v + (wv ? woff[wv - 1] : 0);
  if (i < n) rowstart[i] = incl - val;  // local exclusive
  if (tid == 1023) bsum[blockIdx.x] = woff[15];
}

// ---- phase 2 — scan block sums (<=64 blocks), write grand total ------------
__global__ __launch_bounds__(64) void scan2(const int* __restrict__ bsum,
                                            int* __restrict__ boff,
                                            int* __restrict__ rowstart, int nb,
                                            int n) {
  const int tid = threadIdx.x;
  int v = (tid < nb) ? bsum[tid] : 0;
#pragma unroll
  for (int off = 1; off < 64; off <<= 1) {
    const int o = __shfl_up(v, off);
    if (tid >= off) v += o;
  }
  if (tid < nb) boff[tid] = v;  // inclusive
  if (tid == nb - 1) rowstart[n] = v;
}

// ---- phase 3 — add block offsets -------------------------------------------
__global__ __launch_bounds__(1024) void scan3(int* __restrict__ rowstart,
                                              const int* __restrict__ boff,
                                              int n) {
  const int i = blockIdx.x * 1024 + threadIdx.x;
  if (i < n && blockIdx.x > 0) rowstart[i] += boff[blockIdx.x - 1];
}

// ---- scatter into CSR with precomputed e, packed (dst, e) 8B ---------------
__global__ void scatter_kernel(const int* __restrict__ edge,
                               const int* __restrict__ rowstart,
                               int* __restrict__ cursor,
                               const float* __restrict__ s,
                               const float* __restrict__ t,
                               int2* __restrict__ sde, int E) {
  const int e = blockIdx.x * 256 + threadIdx.x;
  if (e < E) {
    const int src = edge[e];
    const int dst = edge[E + e];
    const float logit = s[src] + t[dst];
    const float lr = logit > 0.f ? logit : ALPHA * logit;
    const float ev = __expf(-lr);
    const int p = atomicAdd(&cursor[src], 1);
    sde[rowstart[src] + p] = make_int2(dst, __float_as_int(ev));
  }
}

// ---- aggregation: wave per row, lane = 4 features, 8B gathers, unroll-4 ----
__global__ __launch_bounds__(256) void agg_kernel(
    const __half* __restrict__ h, const int* __restrict__ rowstart,
    const int2* __restrict__ sde, float* __restrict__ out, int n) {
  const int w = threadIdx.x >> 6, l = threadIdx.x & 63;
  const int row = blockIdx.x * 4 + w;
  if (row >= n) return;
  const int start = rowstart[row], end = rowstart[row + 1];
  const size_t fo = (size_t)l * 4;
  float a0 = 0.f, a1 = 0.f, a2 = 0.f, a3 = 0.f, rs = 0.f;
  int j = start;
  for (; j + 3 < end; j += 4) {
    const int2 p0 = sde[j], p1 = sde[j + 1], p2 = sde[j + 2], p3 = sde[j + 3];
    const half4 v0 = *(const half4*)(h + (size_t)p0.x * 256 + fo);
    const half4 v1 = *(const half4*)(h + (size_t)p1.x * 256 + fo);
    const half4 v2 = *(const half4*)(h + (size_t)p2.x * 256 + fo);
    const half4 v3 = *(const half4*)(h + (size_t)p3.x * 256 + fo);
    const float e0 = __int_as_float(p0.y), e1 = __int_as_float(p1.y);
    const float e2 = __int_as_float(p2.y), e3 = __int_as_float(p3.y);
    rs += (e0 + e1) + (e2 + e3);
    a0 += e0 * (float)v0[0] + e1 * (float)v1[0] + e2 * (float)v2[0] + e3 * (float)v3[0];
    a1 += e0 * (float)v0[1] + e1 * (float)v1[1] + e2 * (float)v2[1] + e3 * (float)v3[1];
    a2 += e0 * (float)v0[2] + e1 * (float)v1[2] + e2 * (float)v2[2] + e3 * (float)v3[2];
    a3 += e0 * (float)v0[3] + e1 * (float)v1[3] + e2 * (float)v2[3] + e3 * (float)v3[3];
  }
  for (; j < end; ++j) {
    const int2 p = sde[j];
    const half4 v = *(const half4*)(h + (size_t)p.x * 256 + fo);
    const float ev = __int_as_float(p.y);
    rs += ev;
    a0 += ev * (float)v[0];
    a1 += ev * (float)v[1];
    a2 += ev * (float)v[2];
    a3 += ev * (float)v[3];
  }
  const float inv = 1.f / rs;
  float4 o;
  o.x = a0 * inv; o.y = a1 * inv; o.z = a2 * inv; o.w = a3 * inv;
  o.x = o.x > 0.f ? o.x : 0.f;
  o.y = o.y > 0.f ? o.y : 0.f;
  o.z = o.z > 0.f ? o.z : 0.f;
  o.w = o.w > 0.f ? o.w : 0.f;
  *(float4*)(out + (size_t)row * 256 + fo) = o;
}

extern "C" void kernel_launch(void* const* d_in, const int* in_sizes, int n_in,
                              void* d_out, int out_size, void* d_ws,
                              size_t ws_size, hipStream_t stream) {
  const float* x = (const float*)d_in[0];
  const int* edge = (const int*)d_in[1];
  const float* W = (const float*)d_in[2];
  const float* a = (const float*)d_in[3];
  float* out = (float*)d_out;
  const int N = in_sizes[0] / FDIM;  // 50000
  const int E = in_sizes[1] / 2;     // 850000
  const int NB = (N + 1023) / 1024;  // 49

  // workspace layout (keep 8B alignment for sde)
  __half* h = (__half*)d_ws;                           // N*256 fp16
  _Float16* wswz = (_Float16*)(h + (size_t)N * FDIM);  // 65536 halves (128 KB)
  float* s = (float*)(wswz + 8192 * 8);                // N
  float* t = s + N;                                    // N
  int* deg = (int*)(t + N);                            // N
  int* cursor = deg + N;                               // N
  int* rowstart = cursor + N;                          // N+2 (pad, even)
  int* bsum = rowstart + N + 2;                        // 64
  int* boff = bsum + 64;                               // 64
  int2* sde = (int2*)(boff + 64);                      // E packed (dst, e)

  hipMemsetAsync(deg, 0, (size_t)2 * N * sizeof(int), stream);  // deg+cursor

  prep_hist<<<32 + (E + 255) / 256, 256, 0, stream>>>(W, wswz, edge, deg, E);
  gemm_mfma<<<(N + 63) / 64, 256, 0, stream>>>(x, wswz, a, h, s, t, N);
  scan1<<<NB, 1024, 0, stream>>>(deg, rowstart, bsum, N);
  scan2<<<1, 64, 0, stream>>>(bsum, boff, rowstart, NB, N);
  scan3<<<NB, 1024, 0, stream>>>(rowstart, boff, N);
  scatter_kernel<<<(E + 255) / 256, 256, 0, stream>>>(edge, rowstart, cursor, s,
                                                      t, sde, E);
  agg_kernel<<<(N + 3) / 4, 256, 0, stream>>>(h, rowstart, sde, out, N);
}

// Round 6
// 278.878 us; speedup vs baseline: 1.9338x; 1.1437x over previous
//
#include <hip/hip_runtime.h>
#include <hip/hip_fp16.h>

#define FDIM 256
#define ALPHA 0.2f

typedef _Float16 half8 __attribute__((ext_vector_type(8)));
typedef _Float16 half4 __attribute__((ext_vector_type(4)));
typedef float floatx4 __attribute__((ext_vector_type(4)));

// ---- prep W (fp16 chunked W^T image) + edge histogram, fused ---------------
__global__ __launch_bounds__(256) void prep_hist(const float* __restrict__ W,
                                                 _Float16* __restrict__ wswz,
                                                 const int* __restrict__ edge,
                                                 int* __restrict__ deg, int E) {
  if (blockIdx.x < 32) {
    const int g = blockIdx.x * 256 + threadIdx.x;  // 0..8191
    const int kc = g >> 11, L = g & 2047;
    const int n = L >> 3, c = L & 7;
    half8 hv;
#pragma unroll
    for (int j = 0; j < 8; ++j)
      hv[j] = (_Float16)W[(size_t)(kc * 64 + c * 8 + j) * 256 + n];
    *(half8*)(wswz + (size_t)g * 8) = hv;
  } else {
    const int e = (blockIdx.x - 32) * 256 + threadIdx.x;
    if (e < E) atomicAdd(&deg[edge[e]], 1);
  }
}

// ---- GEMM h = x@W, MFMA fp16; epilogue transposes via LDS for wide stores --
#define HT_STRIDE 264  // halves; 528 B/row: 16B-aligned, banks spread
__global__ __launch_bounds__(256) void gemm_mfma(
    const float* __restrict__ x, const _Float16* __restrict__ wswz,
    const float* __restrict__ a, _Float16* __restrict__ h,
    float* __restrict__ s, float* __restrict__ t, int M) {
  __shared__ __align__(16) _Float16 smem[64 * HT_STRIDE];  // 33.8 KB
  _Float16* As = smem;  // first 8 KB used for A staging (XOR-swizzled chunks)
  const int tid = threadIdx.x;
  const int w = tid >> 6, l = tid & 63;
  const int l15 = l & 15, q = l >> 4;
  const int row0 = blockIdx.x * 64;

  floatx4 acc[4][4];
#pragma unroll
  for (int mt = 0; mt < 4; ++mt)
#pragma unroll
    for (int nt = 0; nt < 4; ++nt) acc[mt][nt] = (floatx4){0.f, 0.f, 0.f, 0.f};

  const int id0 = tid, id1 = 256 + tid;
  const int m0 = id0 >> 3, c0 = (id0 & 7) ^ (m0 & 7);
  const int m1 = id1 >> 3, c1 = (id1 & 7) ^ (m1 & 7);
  const int r0 = row0 + m0, r1 = row0 + m1;

  float4 pf[2][2];
  auto loadA = [&](int kc) {
    pf[0][0] = pf[0][1] = pf[1][0] = pf[1][1] = make_float4(0.f, 0.f, 0.f, 0.f);
    if (r0 < M) {
      const float4* p = (const float4*)(x + (size_t)r0 * 256 + kc * 64 + c0 * 8);
      pf[0][0] = p[0];
      pf[0][1] = p[1];
    }
    if (r1 < M) {
      const float4* p = (const float4*)(x + (size_t)r1 * 256 + kc * 64 + c1 * 8);
      pf[1][0] = p[0];
      pf[1][1] = p[1];
    }
  };
  auto storeA = [&]() {
#pragma unroll
    for (int hf = 0; hf < 2; ++hf) {
      half8 hv;
      hv[0] = (_Float16)pf[hf][0].x; hv[1] = (_Float16)pf[hf][0].y;
      hv[2] = (_Float16)pf[hf][0].z; hv[3] = (_Float16)pf[hf][0].w;
      hv[4] = (_Float16)pf[hf][1].x; hv[5] = (_Float16)pf[hf][1].y;
      hv[6] = (_Float16)pf[hf][1].z; hv[7] = (_Float16)pf[hf][1].w;
      *(half8*)(As + (size_t)(hf * 256 + tid) * 8) = hv;
    }
  };

  loadA(0);
  for (int kc = 0; kc < 4; ++kc) {
    storeA();
    half8 bf[2][4];
#pragma unroll
    for (int ks = 0; ks < 2; ++ks) {
      const int c = ks * 4 + q;
#pragma unroll
      for (int nt = 0; nt < 4; ++nt) {
        const int n = w * 64 + nt * 16 + l15;
        bf[ks][nt] = *(const half8*)(wswz + (size_t)(kc * 2048 + n * 8 + c) * 8);
      }
    }
    __syncthreads();
    if (kc < 3) loadA(kc + 1);
#pragma unroll
    for (int ks = 0; ks < 2; ++ks) {
      const int c = ks * 4 + q;
      half8 af[4];
#pragma unroll
      for (int mt = 0; mt < 4; ++mt) {
        const int m = mt * 16 + l15;
        af[mt] = *(const half8*)(As + (size_t)(m * 8 + (c ^ (m & 7))) * 8);
      }
#pragma unroll
      for (int mt = 0; mt < 4; ++mt)
#pragma unroll
        for (int nt = 0; nt < 4; ++nt)
          acc[mt][nt] = __builtin_amdgcn_mfma_f32_16x16x32_f16(
              af[mt], bf[ks][nt], acc[mt][nt], 0, 0, 0);
    }
    __syncthreads();
  }

  // ---- epilogue: C/D layout -> LDS row-major fp16 tile -----------------
  // C/D: row = mt*16 + q*4 + r, col = w*64 + nt*16 + l15
#pragma unroll
  for (int mt = 0; mt < 4; ++mt)
#pragma unroll
    for (int nt = 0; nt < 4; ++nt)
#pragma unroll
      for (int r = 0; r < 4; ++r)
        smem[(size_t)(mt * 16 + q * 4 + r) * HT_STRIDE + w * 64 + nt * 16 +
             l15] = (_Float16)acc[mt][nt][r];
  __syncthreads();

  // coalesced 16B stores of h: 8 passes, wave-contiguous rows
  const int w8 = tid >> 5;          // 0..7
  const int colh = (tid & 31) * 8;  // 0..248
#pragma unroll
  for (int p = 0; p < 8; ++p) {
    const int rl = p * 8 + w8;
    const int row = row0 + rl;
    if (row < M)
      *(half8*)(h + (size_t)row * 256 + colh) =
          *(const half8*)(smem + (size_t)rl * HT_STRIDE + colh);
  }

  // s/t from the LDS tile: thread = (row, quarter), float4 a-loads, shfl-reduce
  const int r8 = tid >> 2, seg = tid & 3;
  float sp = 0.f, tp = 0.f;
#pragma unroll
  for (int c8 = 0; c8 < 8; ++c8) {
    const int col = seg * 64 + c8 * 8;
    const half8 hv = *(const half8*)(smem + (size_t)r8 * HT_STRIDE + col);
    const float4 a0 = *(const float4*)(a + col);
    const float4 a1 = *(const float4*)(a + col + 4);
    const float4 b0 = *(const float4*)(a + 256 + col);
    const float4 b1 = *(const float4*)(a + 256 + col + 4);
    sp += (float)hv[0] * a0.x + (float)hv[1] * a0.y + (float)hv[2] * a0.z +
          (float)hv[3] * a0.w + (float)hv[4] * a1.x + (float)hv[5] * a1.y +
          (float)hv[6] * a1.z + (float)hv[7] * a1.w;
    tp += (float)hv[0] * b0.x + (float)hv[1] * b0.y + (float)hv[2] * b0.z +
          (float)hv[3] * b0.w + (float)hv[4] * b1.x + (float)hv[5] * b1.y +
          (float)hv[6] * b1.z + (float)hv[7] * b1.w;
  }
  sp += __shfl_xor(sp, 1);
  sp += __shfl_xor(sp, 2);
  tp += __shfl_xor(tp, 1);
  tp += __shfl_xor(tp, 2);
  if (seg == 0 && row0 + r8 < M) {
    s[row0 + r8] = sp;
    t[row0 + r8] = tp;
  }
}

// ---- multi-block scan -------------------------------------------------------
__global__ __launch_bounds__(1024) void scan1(const int* __restrict__ deg,
                                              int* __restrict__ rowstart,
                                              int* __restrict__ bsum, int n) {
  const int tid = threadIdx.x;
  const int i = blockIdx.x * 1024 + tid;
  const int val = (i < n) ? deg[i] : 0;
  const int lane = tid & 63, wv = tid >> 6;
  int v = val;
#pragma unroll
  for (int off = 1; off < 64; off <<= 1) {
    const int o = __shfl_up(v, off);
    if (lane >= off) v += o;
  }
  __shared__ int wsum[16];
  __shared__ int woff[16];
  if (lane == 63) wsum[wv] = v;
  __syncthreads();
  if (tid < 16) {
    int wv2 = wsum[tid];
#pragma unroll
    for (int off = 1; off < 16; off <<= 1) {
      const int o = __shfl_up(wv2, off);
      if (tid >= off) wv2 += o;
    }
    woff[tid] = wv2;
  }
  __syncthreads();
  const int incl = v + (wv ? woff[wv - 1] : 0);
  if (i < n) rowstart[i] = incl - val;
  if (tid == 1023) bsum[blockIdx.x] = woff[15];
}

__global__ __launch_bounds__(64) void scan2(const int* __restrict__ bsum,
                                            int* __restrict__ boff,
                                            int* __restrict__ rowstart, int nb,
                                            int n) {
  const int tid = threadIdx.x;
  int v = (tid < nb) ? bsum[tid] : 0;
#pragma unroll
  for (int off = 1; off < 64; off <<= 1) {
    const int o = __shfl_up(v, off);
    if (tid >= off) v += o;
  }
  if (tid < nb) boff[tid] = v;
  if (tid == nb - 1) rowstart[n] = v;
}

__global__ __launch_bounds__(1024) void scan3(int* __restrict__ rowstart,
                                              const int* __restrict__ boff,
                                              int n) {
  const int i = blockIdx.x * 1024 + threadIdx.x;
  if (i < n && blockIdx.x > 0) rowstart[i] += boff[blockIdx.x - 1];
}

// ---- scatter into CSR with precomputed e, packed (dst, e) 8B ---------------
__global__ void scatter_kernel(const int* __restrict__ edge,
                               const int* __restrict__ rowstart,
                               int* __restrict__ cursor,
                               const float* __restrict__ s,
                               const float* __restrict__ t,
                               int2* __restrict__ sde, int E) {
  const int e = blockIdx.x * 256 + threadIdx.x;
  if (e < E) {
    const int src = edge[e];
    const int dst = edge[E + e];
    const float logit = s[src] + t[dst];
    const float lr = logit > 0.f ? logit : ALPHA * logit;
    const float ev = __expf(-lr);
    const int p = atomicAdd(&cursor[src], 1);
    sde[rowstart[src] + p] = make_int2(dst, __float_as_int(ev));
  }
}

// ---- aggregation: wave per row, lane = 4 features, 8B gathers, unroll-4 ----
__global__ __launch_bounds__(256) void agg_kernel(
    const __half* __restrict__ h, const int* __restrict__ rowstart,
    const int2* __restrict__ sde, float* __restrict__ out, int n) {
  const int w = threadIdx.x >> 6, l = threadIdx.x & 63;
  const int row = blockIdx.x * 4 + w;
  if (row >= n) return;
  const int start = rowstart[row], end = rowstart[row + 1];
  const size_t fo = (size_t)l * 4;
  float a0 = 0.f, a1 = 0.f, a2 = 0.f, a3 = 0.f, rs = 0.f;
  int j = start;
  for (; j + 3 < end; j += 4) {
    const int2 p0 = sde[j], p1 = sde[j + 1], p2 = sde[j + 2], p3 = sde[j + 3];
    const half4 v0 = *(const half4*)(h + (size_t)p0.x * 256 + fo);
    const half4 v1 = *(const half4*)(h + (size_t)p1.x * 256 + fo);
    const half4 v2 = *(const half4*)(h + (size_t)p2.x * 256 + fo);
    const half4 v3 = *(const half4*)(h + (size_t)p3.x * 256 + fo);
    const float e0 = __int_as_float(p0.y), e1 = __int_as_float(p1.y);
    const float e2 = __int_as_float(p2.y), e3 = __int_as_float(p3.y);
    rs += (e0 + e1) + (e2 + e3);
    a0 += e0 * (float)v0[0] + e1 * (float)v1[0] + e2 * (float)v2[0] + e3 * (float)v3[0];
    a1 += e0 * (float)v0[1] + e1 * (float)v1[1] + e2 * (float)v2[1] + e3 * (float)v3[1];
    a2 += e0 * (float)v0[2] + e1 * (float)v1[2] + e2 * (float)v2[2] + e3 * (float)v3[2];
    a3 += e0 * (float)v0[3] + e1 * (float)v1[3] + e2 * (float)v2[3] + e3 * (float)v3[3];
  }
  for (; j < end; ++j) {
    const int2 p = sde[j];
    const half4 v = *(const half4*)(h + (size_t)p.x * 256 + fo);
    const float ev = __int_as_float(p.y);
    rs += ev;
    a0 += ev * (float)v[0];
    a1 += ev * (float)v[1];
    a2 += ev * (float)v[2];
    a3 += ev * (float)v[3];
  }
  const float inv = 1.f / rs;
  float4 o;
  o.x = a0 * inv; o.y = a1 * inv; o.z = a2 * inv; o.w = a3 * inv;
  o.x = o.x > 0.f ? o.x : 0.f;
  o.y = o.y > 0.f ? o.y : 0.f;
  o.z = o.z > 0.f ? o.z : 0.f;
  o.w = o.w > 0.f ? o.w : 0.f;
  *(float4*)(out + (size_t)row * 256 + fo) = o;
}

extern "C" void kernel_launch(void* const* d_in, const int* in_sizes, int n_in,
                              void* d_out, int out_size, void* d_ws,
                              size_t ws_size, hipStream_t stream) {
  const float* x = (const float*)d_in[0];
  const int* edge = (const int*)d_in[1];
  const float* W = (const float*)d_in[2];
  const float* a = (const float*)d_in[3];
  float* out = (float*)d_out;
  const int N = in_sizes[0] / FDIM;  // 50000
  const int E = in_sizes[1] / 2;     // 850000
  const int NB = (N + 1023) / 1024;  // 49

  __half* h = (__half*)d_ws;                           // N*256 fp16
  _Float16* wswz = (_Float16*)(h + (size_t)N * FDIM);  // 65536 halves (128 KB)
  float* s = (float*)(wswz + 8192 * 8);                // N
  float* t = s + N;                                    // N
  int* deg = (int*)(t + N);                            // N
  int* cursor = deg + N;                               // N
  int* rowstart = cursor + N;                          // N+2
  int* bsum = rowstart + N + 2;                        // 64
  int* boff = bsum + 64;                               // 64
  int2* sde = (int2*)(boff + 64);                      // E packed (dst, e)

  hipMemsetAsync(deg, 0, (size_t)2 * N * sizeof(int), stream);  // deg+cursor

  prep_hist<<<32 + (E + 255) / 256, 256, 0, stream>>>(W, wswz, edge, deg, E);
  gemm_mfma<<<(N + 63) / 64, 256, 0, stream>>>(x, wswz, a, (_Float16*)h, s, t,
                                               N);
  scan1<<<NB, 1024, 0, stream>>>(deg, rowstart, bsum, N);
  scan2<<<1, 64, 0, stream>>>(bsum, boff, rowstart, NB, N);
  scan3<<<NB, 1024, 0, stream>>>(rowstart, boff, N);
  scatter_kernel<<<(E + 255) / 256, 256, 0, stream>>>(edge, rowstart, cursor, s,
                                                      t, sde, E);
  agg_kernel<<<(N + 3) / 4, 256, 0, stream>>>(h, rowstart, sde, out, N);
}

// Round 7
// 272.228 us; speedup vs baseline: 1.9811x; 1.0244x over previous
//
#include <hip/hip_runtime.h>
#include <hip/hip_fp16.h>

#define FDIM 256
#define ALPHA 0.2f

typedef _Float16 half8 __attribute__((ext_vector_type(8)));
typedef float floatx4 __attribute__((ext_vector_type(4)));

// ---- prep W (fp16 chunked W^T image) + edge histogram, fused ---------------
__global__ __launch_bounds__(256) void prep_hist(const float* __restrict__ W,
                                                 _Float16* __restrict__ wswz,
                                                 const int* __restrict__ edge,
                                                 int* __restrict__ deg, int E) {
  if (blockIdx.x < 32) {
    const int g = blockIdx.x * 256 + threadIdx.x;  // 0..8191
    const int kc = g >> 11, L = g & 2047;
    const int n = L >> 3, c = L & 7;
    half8 hv;
#pragma unroll
    for (int j = 0; j < 8; ++j)
      hv[j] = (_Float16)W[(size_t)(kc * 64 + c * 8 + j) * 256 + n];
    *(half8*)(wswz + (size_t)g * 8) = hv;
  } else {
    const int e = (blockIdx.x - 32) * 256 + threadIdx.x;
    if (e < E) atomicAdd(&deg[edge[e]], 1);
  }
}

// ---- GEMM h = x@W, MFMA fp16; epilogue transposes via LDS for wide stores --
#define HT_STRIDE 264
__global__ __launch_bounds__(256) void gemm_mfma(
    const float* __restrict__ x, const _Float16* __restrict__ wswz,
    const float* __restrict__ a, _Float16* __restrict__ h,
    float* __restrict__ s, float* __restrict__ t, int M) {
  __shared__ __align__(16) _Float16 smem[64 * HT_STRIDE];  // 33.8 KB
  _Float16* As = smem;
  const int tid = threadIdx.x;
  const int w = tid >> 6, l = tid & 63;
  const int l15 = l & 15, q = l >> 4;
  const int row0 = blockIdx.x * 64;

  floatx4 acc[4][4];
#pragma unroll
  for (int mt = 0; mt < 4; ++mt)
#pragma unroll
    for (int nt = 0; nt < 4; ++nt) acc[mt][nt] = (floatx4){0.f, 0.f, 0.f, 0.f};

  const int id0 = tid, id1 = 256 + tid;
  const int m0 = id0 >> 3, c0 = (id0 & 7) ^ (m0 & 7);
  const int m1 = id1 >> 3, c1 = (id1 & 7) ^ (m1 & 7);
  const int r0 = row0 + m0, r1 = row0 + m1;

  float4 pf[2][2];
  auto loadA = [&](int kc) {
    pf[0][0] = pf[0][1] = pf[1][0] = pf[1][1] = make_float4(0.f, 0.f, 0.f, 0.f);
    if (r0 < M) {
      const float4* p = (const float4*)(x + (size_t)r0 * 256 + kc * 64 + c0 * 8);
      pf[0][0] = p[0];
      pf[0][1] = p[1];
    }
    if (r1 < M) {
      const float4* p = (const float4*)(x + (size_t)r1 * 256 + kc * 64 + c1 * 8);
      pf[1][0] = p[0];
      pf[1][1] = p[1];
    }
  };
  auto storeA = [&]() {
#pragma unroll
    for (int hf = 0; hf < 2; ++hf) {
      half8 hv;
      hv[0] = (_Float16)pf[hf][0].x; hv[1] = (_Float16)pf[hf][0].y;
      hv[2] = (_Float16)pf[hf][0].z; hv[3] = (_Float16)pf[hf][0].w;
      hv[4] = (_Float16)pf[hf][1].x; hv[5] = (_Float16)pf[hf][1].y;
      hv[6] = (_Float16)pf[hf][1].z; hv[7] = (_Float16)pf[hf][1].w;
      *(half8*)(As + (size_t)(hf * 256 + tid) * 8) = hv;
    }
  };

  loadA(0);
  for (int kc = 0; kc < 4; ++kc) {
    storeA();
    half8 bf[2][4];
#pragma unroll
    for (int ks = 0; ks < 2; ++ks) {
      const int c = ks * 4 + q;
#pragma unroll
      for (int nt = 0; nt < 4; ++nt) {
        const int n = w * 64 + nt * 16 + l15;
        bf[ks][nt] = *(const half8*)(wswz + (size_t)(kc * 2048 + n * 8 + c) * 8);
      }
    }
    __syncthreads();
    if (kc < 3) loadA(kc + 1);
#pragma unroll
    for (int ks = 0; ks < 2; ++ks) {
      const int c = ks * 4 + q;
      half8 af[4];
#pragma unroll
      for (int mt = 0; mt < 4; ++mt) {
        const int m = mt * 16 + l15;
        af[mt] = *(const half8*)(As + (size_t)(m * 8 + (c ^ (m & 7))) * 8);
      }
#pragma unroll
      for (int mt = 0; mt < 4; ++mt)
#pragma unroll
        for (int nt = 0; nt < 4; ++nt)
          acc[mt][nt] = __builtin_amdgcn_mfma_f32_16x16x32_f16(
              af[mt], bf[ks][nt], acc[mt][nt], 0, 0, 0);
    }
    __syncthreads();
  }

  // epilogue: C/D -> LDS row-major -> coalesced 16B stores
#pragma unroll
  for (int mt = 0; mt < 4; ++mt)
#pragma unroll
    for (int nt = 0; nt < 4; ++nt)
#pragma unroll
      for (int r = 0; r < 4; ++r)
        smem[(size_t)(mt * 16 + q * 4 + r) * HT_STRIDE + w * 64 + nt * 16 +
             l15] = (_Float16)acc[mt][nt][r];
  __syncthreads();

  const int w8 = tid >> 5;
  const int colh = (tid & 31) * 8;
#pragma unroll
  for (int p = 0; p < 8; ++p) {
    const int rl = p * 8 + w8;
    const int row = row0 + rl;
    if (row < M)
      *(half8*)(h + (size_t)row * 256 + colh) =
          *(const half8*)(smem + (size_t)rl * HT_STRIDE + colh);
  }

  // s/t from LDS tile
  const int r8 = tid >> 2, seg = tid & 3;
  float sp = 0.f, tp = 0.f;
#pragma unroll
  for (int c8 = 0; c8 < 8; ++c8) {
    const int col = seg * 64 + c8 * 8;
    const half8 hv = *(const half8*)(smem + (size_t)r8 * HT_STRIDE + col);
    const float4 a0 = *(const float4*)(a + col);
    const float4 a1 = *(const float4*)(a + col + 4);
    const float4 b0 = *(const float4*)(a + 256 + col);
    const float4 b1 = *(const float4*)(a + 256 + col + 4);
    sp += (float)hv[0] * a0.x + (float)hv[1] * a0.y + (float)hv[2] * a0.z +
          (float)hv[3] * a0.w + (float)hv[4] * a1.x + (float)hv[5] * a1.y +
          (float)hv[6] * a1.z + (float)hv[7] * a1.w;
    tp += (float)hv[0] * b0.x + (float)hv[1] * b0.y + (float)hv[2] * b0.z +
          (float)hv[3] * b0.w + (float)hv[4] * b1.x + (float)hv[5] * b1.y +
          (float)hv[6] * b1.z + (float)hv[7] * b1.w;
  }
  sp += __shfl_xor(sp, 1);
  sp += __shfl_xor(sp, 2);
  tp += __shfl_xor(tp, 1);
  tp += __shfl_xor(tp, 2);
  if (seg == 0 && row0 + r8 < M) {
    s[row0 + r8] = sp;
    t[row0 + r8] = tp;
  }
}

// ---- multi-block scan -------------------------------------------------------
__global__ __launch_bounds__(1024) void scan1(const int* __restrict__ deg,
                                              int* __restrict__ rowstart,
                                              int* __restrict__ bsum, int n) {
  const int tid = threadIdx.x;
  const int i = blockIdx.x * 1024 + tid;
  const int val = (i < n) ? deg[i] : 0;
  const int lane = tid & 63, wv = tid >> 6;
  int v = val;
#pragma unroll
  for (int off = 1; off < 64; off <<= 1) {
    const int o = __shfl_up(v, off);
    if (lane >= off) v += o;
  }
  __shared__ int wsum[16];
  __shared__ int woff[16];
  if (lane == 63) wsum[wv] = v;
  __syncthreads();
  if (tid < 16) {
    int wv2 = wsum[tid];
#pragma unroll
    for (int off = 1; off < 16; off <<= 1) {
      const int o = __shfl_up(wv2, off);
      if (tid >= off) wv2 += o;
    }
    woff[tid] = wv2;
  }
  __syncthreads();
  const int incl = v + (wv ? woff[wv - 1] : 0);
  if (i < n) rowstart[i] = incl - val;
  if (tid == 1023) bsum[blockIdx.x] = woff[15];
}

__global__ __launch_bounds__(64) void scan2(const int* __restrict__ bsum,
                                            int* __restrict__ boff,
                                            int* __restrict__ rowstart, int nb,
                                            int n) {
  const int tid = threadIdx.x;
  int v = (tid < nb) ? bsum[tid] : 0;
#pragma unroll
  for (int off = 1; off < 64; off <<= 1) {
    const int o = __shfl_up(v, off);
    if (tid >= off) v += o;
  }
  if (tid < nb) boff[tid] = v;
  if (tid == nb - 1) rowstart[n] = v;
}

// scan3: finalize rowstart AND emit rsc (cursor copy for scatter's atomicAdd)
__global__ __launch_bounds__(1024) void scan3(int* __restrict__ rowstart,
                                              int* __restrict__ rsc,
                                              const int* __restrict__ boff,
                                              int n) {
  const int i = blockIdx.x * 1024 + threadIdx.x;
  if (i < n) {
    const int v = rowstart[i] + (blockIdx.x ? boff[blockIdx.x - 1] : 0);
    rowstart[i] = v;
    rsc[i] = v;
  }
}

// ---- scatter: pos straight from atomicAdd on rsc (no rowstart gather) ------
__global__ void scatter_kernel(const int* __restrict__ edge,
                               int* __restrict__ rsc,
                               const float* __restrict__ s,
                               const float* __restrict__ t,
                               int2* __restrict__ sde, int E) {
  const int e = blockIdx.x * 256 + threadIdx.x;
  if (e < E) {
    const int src = edge[e];
    const int dst = edge[E + e];
    const float logit = s[src] + t[dst];
    const float lr = logit > 0.f ? logit : ALPHA * logit;
    const float ev = __expf(-lr);
    const int pos = atomicAdd(&rsc[src], 1);
    sde[pos] = make_int2(dst, __float_as_int(ev));
  }
}

// ---- aggregation: wave = 2 edges/iter, lane = 8 features (16B gathers) -----
__global__ __launch_bounds__(256) void agg_kernel(
    const _Float16* __restrict__ h, const int* __restrict__ rowstart,
    const int2* __restrict__ sde, float* __restrict__ out, int n) {
  const int w = threadIdx.x >> 6, l = threadIdx.x & 63;
  const int row = blockIdx.x * 4 + w;
  if (row >= n) return;
  const int start = rowstart[row], end = rowstart[row + 1];
  const int half = l >> 5;           // 0: edge j, 1: edge j+1
  const int lh = l & 31;             // lane within half
  const size_t fo = (size_t)lh * 8;  // 8 features = 16 B
  float acc[8] = {};
  float rs = 0.f;
  int j = start;
  for (; j + 8 <= end; j += 8) {
#pragma unroll
    for (int u = 0; u < 4; ++u) {
      const int2 p = sde[j + u * 2 + half];
      const half8 v = *(const half8*)(h + (size_t)p.x * 256 + fo);
      const float e = __int_as_float(p.y);
      rs += e;
#pragma unroll
      for (int k = 0; k < 8; ++k) acc[k] += e * (float)v[k];
    }
  }
  for (; j < end; j += 2) {
    const int idx = j + half;
    const bool valid = idx < end;
    const int2 p = valid ? sde[idx] : make_int2(0, 0);
    const half8 v = *(const half8*)(h + (size_t)p.x * 256 + fo);
    const float e = valid ? __int_as_float(p.y) : 0.f;
    rs += e;
#pragma unroll
    for (int k = 0; k < 8; ++k) acc[k] += e * (float)v[k];
  }
  // combine the two halves
  rs += __shfl_xor(rs, 32);
#pragma unroll
  for (int k = 0; k < 8; ++k) acc[k] += __shfl_xor(acc[k], 32);
  const float inv = 1.f / rs;
  // lane writes one float4: low half covers [lh*8, +4), high [lh*8+4, +4)
  float4 o;
#pragma unroll
  for (int k = 0; k < 4; ++k) {
    const float vv = acc[half * 4 + k] * inv;
    (&o.x)[k] = vv > 0.f ? vv : 0.f;
  }
  *(float4*)(out + (size_t)row * 256 + lh * 8 + half * 4) = o;
}

extern "C" void kernel_launch(void* const* d_in, const int* in_sizes, int n_in,
                              void* d_out, int out_size, void* d_ws,
                              size_t ws_size, hipStream_t stream) {
  const float* x = (const float*)d_in[0];
  const int* edge = (const int*)d_in[1];
  const float* W = (const float*)d_in[2];
  const float* a = (const float*)d_in[3];
  float* out = (float*)d_out;
  const int N = in_sizes[0] / FDIM;  // 50000
  const int E = in_sizes[1] / 2;     // 850000
  const int NB = (N + 1023) / 1024;  // 49

  _Float16* h = (_Float16*)d_ws;                       // N*256 fp16
  _Float16* wswz = h + (size_t)N * FDIM;               // 65536 halves (128 KB)
  float* s = (float*)(wswz + 8192 * 8);                // N
  float* t = s + N;                                    // N
  int* deg = (int*)(t + N);                            // N
  int* rsc = deg + N;                                  // N (cursor copy)
  int* rowstart = rsc + N;                             // N+2
  int* bsum = rowstart + N + 2;                        // 64
  int* boff = bsum + 64;                               // 64
  int2* sde = (int2*)(boff + 64);                      // E packed (dst, e)

  hipMemsetAsync(deg, 0, (size_t)N * sizeof(int), stream);

  prep_hist<<<32 + (E + 255) / 256, 256, 0, stream>>>(W, wswz, edge, deg, E);
  gemm_mfma<<<(N + 63) / 64, 256, 0, stream>>>(x, wswz, a, h, s, t, N);
  scan1<<<NB, 1024, 0, stream>>>(deg, rowstart, bsum, N);
  scan2<<<1, 64, 0, stream>>>(bsum, boff, rowstart, NB, N);
  scan3<<<NB, 1024, 0, stream>>>(rowstart, rsc, boff, N);
  scatter_kernel<<<(E + 255) / 256, 256, 0, stream>>>(edge, rsc, s, t, sde, E);
  agg_kernel<<<(N + 3) / 4, 256, 0, stream>>>(h, rowstart, sde, out, N);
}